// Round 1
// 403.834 us; speedup vs baseline: 1.1095x; 1.1095x over previous
//
#include <hip/hip_runtime.h>

#define LOG2E 1.4426950408889634f

typedef __attribute__((ext_vector_type(8))) short short8;
typedef __attribute__((ext_vector_type(4))) float f32x4;
typedef __attribute__((ext_vector_type(16))) float f32x16;
typedef __attribute__((ext_vector_type(4))) unsigned u32x4;

__device__ inline unsigned short f2bf(float f) {
  unsigned u = __float_as_uint(f);
  u += 0x7fffu + ((u >> 16) & 1u);
  return (unsigned short)(u >> 16);
}

#define MFMA16(a, b, c) __builtin_amdgcn_mfma_f32_16x16x32_bf16((a), (b), (c), 0, 0, 0)
#define MFMA32(a, b, c) __builtin_amdgcn_mfma_f32_32x32x16_bf16((a), (b), (c), 0, 0, 0)

#define GLDS16(gp, lp)                                                              \
  __builtin_amdgcn_global_load_lds((const __attribute__((address_space(1))) void*)(gp), \
                                   (__attribute__((address_space(3))) void*)(lp), 16, 0, 0)

__device__ inline f32x4 zero4() {
  f32x4 z = {0.f, 0.f, 0.f, 0.f};
  return z;
}
__device__ inline f32x16 zero16() {
  f32x16 z = {0.f, 0.f, 0.f, 0.f, 0.f, 0.f, 0.f, 0.f, 0.f, 0.f, 0.f, 0.f, 0.f, 0.f, 0.f, 0.f};
  return z;
}
// dst.lo16 = bf16(a), dst.hi16 = bf16(b)
__device__ inline unsigned cvtpk_bf16(float a, float b) {
  unsigned r;
  asm("v_cvt_pk_bf16_f32 %0, %1, %2" : "=v"(r) : "v"(a), "v"(b));
  return r;
}
// after: a = [a.lo32lanes, b.lo32lanes], b = [a.hi32lanes, b.hi32lanes]
__device__ inline void plswap(unsigned& a, unsigned& b) {
  asm("v_permlane32_swap_b32 %0, %1" : "+v"(a), "+v"(b));
}

// ---------------------------------------------------------------- merged cast fp32 -> bf16 (all 6 arrays, 1 dispatch)
__global__ __launch_bounds__(256) void k_cast6(
    const float* __restrict__ e, const float* __restrict__ q, const float* __restrict__ wq,
    const float* __restrict__ wo, const float* __restrict__ wb, const float* __restrict__ wa,
    unsigned short* __restrict__ eo, unsigned short* __restrict__ qo, unsigned short* __restrict__ wqo,
    unsigned short* __restrict__ woo, unsigned short* __restrict__ wbo, unsigned short* __restrict__ wao) {
  int i = (blockIdx.x * 256 + threadIdx.x) * 4;
  const float* src;
  unsigned short* dst;
  int off;
  if (i < 16777216) { src = e; dst = eo; off = i; }
  else if (i < 25165824) { src = q; dst = qo; off = i - 16777216; }
  else if (i < 26214400) { src = wq; dst = wqo; off = i - 25165824; }
  else if (i < 27262976) { src = wo; dst = woo; off = i - 26214400; }
  else if (i < 27787264) { src = wb; dst = wbo; off = i - 27262976; }
  else { src = wa; dst = wao; off = i - 27787264; }
  float4 v = *(const float4*)(src + off);
  unsigned lo = (unsigned)f2bf(v.x) | ((unsigned)f2bf(v.y) << 16);
  unsigned hi = (unsigned)f2bf(v.z) | ((unsigned)f2bf(v.w) << 16);
  *(uint2*)(dst + off) = make_uint2(lo, hi);
}

// ---------------------------------------------------------------- K1: q = query @ Wq^T (scaled by log2e/8), -> (B,H,SQ,64) bf16
__global__ __launch_bounds__(256, 2) void k_qproj(const unsigned short* __restrict__ A,
                                                  const unsigned short* __restrict__ Bw,
                                                  unsigned short* __restrict__ Qout) {
  __shared__ __align__(16) short As[128 * 32];
  __shared__ __align__(16) short Bs[128 * 32];
  const int K = 1024;
  int tid = threadIdx.x;
  int w = tid >> 6, lane = tid & 63, quad = lane >> 4, c = lane & 15;
  int m0 = blockIdx.x * 128, n0 = blockIdx.y * 128;
  int wm = (w >> 1) * 64, wn = (w & 1) * 64;
  f32x4 acc[4][4];
#pragma unroll
  for (int i = 0; i < 4; i++)
#pragma unroll
    for (int j = 0; j < 4; j++) acc[i][j] = zero4();

  for (int k0 = 0; k0 < K; k0 += 32) {
#pragma unroll
    for (int i = 0; i < 2; i++) {
      int seg = w * 2 + i;
      int bo = seg * 1024 + lane * 16;
      int row = bo >> 6, col = (bo & 63) >> 1;
      GLDS16(A + (size_t)(m0 + row) * K + k0 + col, (char*)As + seg * 1024);
      GLDS16(Bw + (size_t)(n0 + row) * K + k0 + col, (char*)Bs + seg * 1024);
    }
    __syncthreads();
    short8 af[4], bfr[4];
#pragma unroll
    for (int i = 0; i < 4; i++) {
      af[i] = *(const short8*)&As[(wm + i * 16 + c) * 32 + quad * 8];
      bfr[i] = *(const short8*)&Bs[(wn + i * 16 + c) * 32 + quad * 8];
    }
#pragma unroll
    for (int mi = 0; mi < 4; mi++)
#pragma unroll
      for (int ni = 0; ni < 4; ni++) acc[mi][ni] = MFMA16(af[mi], bfr[ni], acc[mi][ni]);
    __syncthreads();
  }
  const float scale = 0.125f * LOG2E;
#pragma unroll
  for (int mi = 0; mi < 4; mi++) {
    int rowb = m0 + wm + mi * 16 + quad * 4;
#pragma unroll
    for (int ni = 0; ni < 4; ni++) {
      int col = n0 + wn + ni * 16 + c;
      int h = col >> 6, d = col & 63;
#pragma unroll
      for (int r = 0; r < 4; r++) {
        int row = rowb + r;
        int b = row >> 11, sq = row & 2047;
        Qout[(((size_t)(b * 16 + h)) * 2048 + sq) * 64 + d] = f2bf(acc[mi][ni][r] * scale);
      }
    }
  }
}

// ---------------------------------------------------------------- K2: c = enc @ Wkva^T, LayerNorm, -> [16384,256] bf16
__global__ __launch_bounds__(256, 2) void k_cln(const unsigned short* __restrict__ E,
                                                const unsigned short* __restrict__ Wa,
                                                const float* __restrict__ g, const float* __restrict__ bb,
                                                unsigned short* __restrict__ Cout) {
  __shared__ __align__(16) short As[64 * 32];
  __shared__ __align__(16) short Bs[256 * 32];
  __shared__ float redS[4][64], redQ[4][64];
  __shared__ float gS[256], bS[256];
  const int K = 1024;
  int tid = threadIdx.x;
  int w = tid >> 6, lane = tid & 63, quad = lane >> 4, c = lane & 15;
  int m0 = blockIdx.x * 64;
  gS[tid] = g[tid];
  bS[tid] = bb[tid];
  f32x4 acc[4][4];
#pragma unroll
  for (int i = 0; i < 4; i++)
#pragma unroll
    for (int j = 0; j < 4; j++) acc[i][j] = zero4();

  for (int k0 = 0; k0 < K; k0 += 32) {
    {
      int bo = w * 1024 + lane * 16;
      int row = bo >> 6, col = (bo & 63) >> 1;
      GLDS16(E + (size_t)(m0 + row) * K + k0 + col, (char*)As + w * 1024);
    }
#pragma unroll
    for (int i = 0; i < 4; i++) {
      int seg = w * 4 + i;
      int bo = seg * 1024 + lane * 16;
      int row = bo >> 6, col = (bo & 63) >> 1;
      GLDS16(Wa + (size_t)row * K + k0 + col, (char*)Bs + seg * 1024);
    }
    __syncthreads();
    short8 af[4], bfr[4];
#pragma unroll
    for (int i = 0; i < 4; i++) {
      af[i] = *(const short8*)&As[(i * 16 + c) * 32 + quad * 8];
      bfr[i] = *(const short8*)&Bs[(w * 64 + i * 16 + c) * 32 + quad * 8];
    }
#pragma unroll
    for (int mi = 0; mi < 4; mi++)
#pragma unroll
      for (int ni = 0; ni < 4; ni++) acc[mi][ni] = MFMA16(af[mi], bfr[ni], acc[mi][ni]);
    __syncthreads();
  }
  float ps[4][4], pq[4][4];
#pragma unroll
  for (int mi = 0; mi < 4; mi++)
#pragma unroll
    for (int r = 0; r < 4; r++) {
      float s = 0.f, q = 0.f;
#pragma unroll
      for (int ni = 0; ni < 4; ni++) {
        float x = acc[mi][ni][r];
        s += x;
        q += x * x;
      }
      for (int m = 1; m < 16; m <<= 1) {
        s += __shfl_xor(s, m, 64);
        q += __shfl_xor(q, m, 64);
      }
      ps[mi][r] = s;
      pq[mi][r] = q;
    }
  if (c == 0) {
#pragma unroll
    for (int mi = 0; mi < 4; mi++)
#pragma unroll
      for (int r = 0; r < 4; r++) {
        int row = mi * 16 + quad * 4 + r;
        redS[w][row] = ps[mi][r];
        redQ[w][row] = pq[mi][r];
      }
  }
  __syncthreads();
  float muv[4][4], rsv[4][4];
#pragma unroll
  for (int mi = 0; mi < 4; mi++)
#pragma unroll
    for (int r = 0; r < 4; r++) {
      int row = mi * 16 + quad * 4 + r;
      float S = redS[0][row] + redS[1][row] + redS[2][row] + redS[3][row];
      float Q = redQ[0][row] + redQ[1][row] + redQ[2][row] + redQ[3][row];
      float mu = S * (1.f / 256.f);
      float var = Q * (1.f / 256.f) - mu * mu;
      muv[mi][r] = mu;
      rsv[mi][r] = rsqrtf(var + 1e-5f);
    }
#pragma unroll
  for (int mi = 0; mi < 4; mi++)
#pragma unroll
    for (int ni = 0; ni < 4; ni++) {
      int col = w * 64 + ni * 16 + c;
#pragma unroll
      for (int r = 0; r < 4; r++) {
        int row = m0 + mi * 16 + quad * 4 + r;
        float y = (acc[mi][ni][r] - muv[mi][r]) * rsv[mi][r] * gS[col] + bS[col];
        Cout[(size_t)row * 256 + col] = f2bf(y);
      }
    }
}

// ---------------------------------------------------------------- K3: kv = c_ln @ Wkvb^T -> K, V in attn fragment-major tiles
// New layout (per bh, per 64-key tile kt, 8 KiB each, ushort units):
//  K: idx = bh*262144 + kt*4096 + ((half*4 + ds)*64 + (key&31) + 32*((d>>3)&1))*8 + (d&7)
//     where half = (key_in_tile)>>5, ds = d>>4       [A-frag of mfma_32x32x16: row=l&31=key, col=8*(l>>5)+j]
//  V: idx = bh*262144 + kt*4096 + ((dt*4 + s)*64 + (d&31) + 32*((k>>3)&1))*8 + (k&7)
//     where dt = d>>5, s = (k_in_tile)>>4             [B-frag: col=l&31=d, row=8*(l>>5)+j]
// This makes k_attn's global_load_lds staging fully linear (1 KiB coalesced segs)
// and every ds_read base+lane*16+imm (conflict-free).
__global__ __launch_bounds__(256, 2) void k_kv(const unsigned short* __restrict__ A,
                                               const unsigned short* __restrict__ Bw,
                                               unsigned short* __restrict__ Kb,
                                               unsigned short* __restrict__ Vb) {
  __shared__ __align__(16) short As[128 * 32];
  __shared__ __align__(16) short Bs[128 * 32];
  const int K = 256;
  int tid = threadIdx.x;
  int w = tid >> 6, lane = tid & 63, quad = lane >> 4, c = lane & 15;
  int m0 = blockIdx.x * 128, n0 = blockIdx.y * 128;
  int wm = (w >> 1) * 64, wn = (w & 1) * 64;
  f32x4 acc[4][4];
#pragma unroll
  for (int i = 0; i < 4; i++)
#pragma unroll
    for (int j = 0; j < 4; j++) acc[i][j] = zero4();

  for (int k0 = 0; k0 < K; k0 += 32) {
#pragma unroll
    for (int i = 0; i < 2; i++) {
      int seg = w * 2 + i;
      int bo = seg * 1024 + lane * 16;
      int row = bo >> 6, col = (bo & 63) >> 1;
      GLDS16(A + (size_t)(m0 + row) * K + k0 + col, (char*)As + seg * 1024);
      GLDS16(Bw + (size_t)(n0 + row) * K + k0 + col, (char*)Bs + seg * 1024);
    }
    __syncthreads();
    short8 af[4], bfr[4];
#pragma unroll
    for (int i = 0; i < 4; i++) {
      af[i] = *(const short8*)&As[(wm + i * 16 + c) * 32 + quad * 8];
      bfr[i] = *(const short8*)&Bs[(wn + i * 16 + c) * 32 + quad * 8];
    }
#pragma unroll
    for (int mi = 0; mi < 4; mi++)
#pragma unroll
      for (int ni = 0; ni < 4; ni++) acc[mi][ni] = MFMA16(af[mi], bfr[ni], acc[mi][ni]);
    __syncthreads();
  }
#pragma unroll
  for (int mi = 0; mi < 4; mi++) {
    int rowb = m0 + wm + mi * 16 + quad * 4;
#pragma unroll
    for (int ni = 0; ni < 4; ni++) {
      int col = n0 + wn + ni * 16 + c;
      int h = col >> 7, rr = col & 127;
#pragma unroll
      for (int r = 0; r < 4; r++) {
        int row = rowb + r;
        int b = row >> 12, sk = row & 4095;
        int kt = sk >> 6, ki = sk & 63;
        size_t base = ((size_t)(b * 16 + h)) * 262144 + (size_t)kt * 4096;
        float x = acc[mi][ni][r];
        if (rr < 64) {
          int d = rr;
          int half = ki >> 5, l31k = ki & 31, ds = d >> 4, dhi = (d >> 3) & 1, j = d & 7;
          Kb[base + (size_t)((half * 4 + ds) * 64 + l31k + 32 * dhi) * 8 + j] = f2bf(x);
        } else {
          int d = rr - 64;
          int dt = d >> 5, sg = ki >> 4, khi = (ki >> 3) & 1, j = ki & 7;
          Vb[base + (size_t)((dt * 4 + sg) * 64 + (d & 31) + 32 * khi) * 8 + j] = f2bf(x);
        }
      }
    }
  }
}

// ---------------------------------------------------------------- K4: flash attention, 32x32x16 MFMA, P fully in-register.
// Block = 2 waves x 64 q-rows = 128 q; grid (16 qt, 64 bh) = 1024 blocks = 4/CU.
// Per kt (64 keys): S^T = K Q^T via 32x32x16 (C: col=l&31=q, row=(r&3)+8*(r>>2)+4*(l>>5)=key);
// exp2 -> v_cvt_pk_bf16_f32 pairs -> v_permlane32_swap_b32 ((u0,u2),(u1,u3)) gives the PV
// A-fragment directly (T12/m214 pattern) -- no P LDS round-trip.
// K/V arrive in fragment-major tiles (see k_kv), so staging is 16 linear 1KiB GLDS segs
// (wave0=K, wave1=V) and all ds_reads are base+lane*16+imm: zero bank conflicts.
// Double-buffered KV (32 KiB), counted s_waitcnt vmcnt(8) + raw s_barrier (m201 template):
// loads for kt are issued at end of kt-2, covered by a full iteration of compute.
// LDS pipe: 16 b128/wave-kt for 64q*64k work = ~98K cyc/CU < MFMA 132K -> MFMA-bound.
__global__ __launch_bounds__(128, 2) void k_attn(const unsigned short* __restrict__ Qb,
                                                 const unsigned short* __restrict__ Kb,
                                                 const unsigned short* __restrict__ Vb,
                                                 unsigned short* __restrict__ Ob) {
  __shared__ __align__(16) short KVs[16384];  // 2 bufs x (K 8KiB | V 8KiB) = 32 KiB
  int tid = threadIdx.x;
  int w = tid >> 6, lane = tid & 63;
  int l31 = lane & 31, hi = lane >> 5;
  int qt = blockIdx.x, bh = blockIdx.y;

  const char* Kg = (const char*)Kb + (size_t)bh * 524288;
  const char* Vg = (const char*)Vb + (size_t)bh * 524288;
  const char* sgbase = (w ? Vg : Kg) + lane * 16;  // wave0 stages K, wave1 stages V

  // Q fragments (B-operand): lane needs Q[q = l&31 of its 32-block][d = 16*ds + 8*hi + 0..7]
  const unsigned short* Qrow = Qb + ((size_t)bh * 2048 + qt * 128 + w * 64 + l31) * 64 + hi * 8;
  short8 qf[2][4];
#pragma unroll
  for (int qb = 0; qb < 2; qb++)
#pragma unroll
    for (int ds = 0; ds < 4; ds++) qf[qb][ds] = *(const short8*)(Qrow + qb * 2048 + ds * 16);

  f32x16 O[2][2];
  float lp[2] = {0.f, 0.f};
#pragma unroll
  for (int i = 0; i < 2; i++)
#pragma unroll
    for (int j = 0; j < 2; j++) O[i][j] = zero16();

  // prologue: stage kt=0 -> buf0, kt=1 -> buf1 (8 x 1KiB linear segs per wave per tile)
#pragma unroll
  for (int i = 0; i < 8; i++) GLDS16(sgbase + i * 1024, (char*)KVs + w * 8192 + i * 1024);
#pragma unroll
  for (int i = 0; i < 8; i++) GLDS16(sgbase + 8192 + i * 1024, (char*)KVs + 16384 + w * 8192 + i * 1024);
  sgbase += 16384;  // next tile to stage = kt+2

  for (int kt = 0; kt < 64; kt++) {
    // buf[kt&1] loads are the 8 oldest outstanding; 8 newest (next buf) stay in flight.
    if (kt == 63)
      asm volatile("s_waitcnt vmcnt(0)\n\ts_barrier" ::: "memory");
    else
      asm volatile("s_waitcnt vmcnt(8)\n\ts_barrier" ::: "memory");

    const char* Kl = (const char*)KVs + (kt & 1) * 16384 + lane * 16;
    const char* Vl = Kl + 8192;

#pragma unroll
    for (int h = 0; h < 2; h++) {  // 32-key halves
      short8 kf[4];
#pragma unroll
      for (int ds = 0; ds < 4; ds++) kf[ds] = *(const short8*)(Kl + (h * 4 + ds) * 1024);
      short8 paf[2][2];  // [qb][16-key slice]
#pragma unroll
      for (int qb = 0; qb < 2; qb++) {
        f32x16 S = zero16();
#pragma unroll
        for (int ds = 0; ds < 4; ds++) S = MFMA32(kf[ds], qf[qb][ds], S);
        float pp[8];
        unsigned u[8];
#pragma unroll
        for (int m = 0; m < 8; m++) {
          float p0 = __builtin_amdgcn_exp2f(S[2 * m]);
          float p1 = __builtin_amdgcn_exp2f(S[2 * m + 1]);
          pp[m] = p0 + p1;
          u[m] = cvtpk_bf16(p0, p1);
        }
        lp[qb] += ((pp[0] + pp[1]) + (pp[2] + pp[3])) + ((pp[4] + pp[5]) + (pp[6] + pp[7]));
        // transpose to A-frag: word m of A(s) = u[(m&1)+4s+2*hi] from src half m>>1
        plswap(u[0], u[2]);
        plswap(u[1], u[3]);
        plswap(u[4], u[6]);
        plswap(u[5], u[7]);
        u32x4 w0 = {u[0], u[1], u[2], u[3]};
        u32x4 w1 = {u[4], u[5], u[6], u[7]};
        paf[qb][0] = __builtin_bit_cast(short8, w0);
        paf[qb][1] = __builtin_bit_cast(short8, w1);
      }
      // PV: O[qb][dt] += P(slice) V(slice)
#pragma unroll
      for (int dt = 0; dt < 2; dt++)
#pragma unroll
        for (int s2 = 0; s2 < 2; s2++) {
          short8 vf = *(const short8*)(Vl + (dt * 4 + h * 2 + s2) * 1024);
#pragma unroll
          for (int qb = 0; qb < 2; qb++) O[qb][dt] = MFMA32(paf[qb][s2], vf, O[qb][dt]);
        }
    }
    asm volatile("s_barrier" ::: "memory");  // all waves done reading buf[kt&1]
    if (kt < 62) {
#pragma unroll
      for (int i = 0; i < 8; i++)
        GLDS16(sgbase + i * 1024, (char*)KVs + (kt & 1) * 16384 + w * 8192 + i * 1024);
      sgbase += 8192;
    }
  }

  // l: lanes l and l+32 hold complementary key-partials for q = l&31
#pragma unroll
  for (int qb = 0; qb < 2; qb++) lp[qb] += __shfl_xor(lp[qb], 32, 64);
  int b = bh >> 4, hh = bh & 15;
#pragma unroll
  for (int qb = 0; qb < 2; qb++) {
#pragma unroll
    for (int r = 0; r < 16; r++) {
      int qrow = (r & 3) + 8 * (r >> 2) + 4 * hi;
      float inv = __builtin_amdgcn_rcpf(__shfl(lp[qb], qrow, 64));
      size_t orow = ((size_t)b * 2048 + qt * 128 + w * 64 + qb * 32 + qrow) * 1024 + hh * 64 + l31;
      Ob[orow] = f2bf(O[qb][0][r] * inv);
      Ob[orow + 32] = f2bf(O[qb][1][r] * inv);
    }
  }
}

// ---------------------------------------------------------------- K5: out = O @ Wout^T -> fp32
__global__ __launch_bounds__(256, 2) void k_out(const unsigned short* __restrict__ A,
                                                const unsigned short* __restrict__ Bw,
                                                float* __restrict__ Out) {
  __shared__ __align__(16) short As[128 * 32];
  __shared__ __align__(16) short Bs[128 * 32];
  const int K = 1024;
  int tid = threadIdx.x;
  int w = tid >> 6, lane = tid & 63, quad = lane >> 4, c = lane & 15;
  int m0 = blockIdx.x * 128, n0 = blockIdx.y * 128;
  int wm = (w >> 1) * 64, wn = (w & 1) * 64;
  f32x4 acc[4][4];
#pragma unroll
  for (int i = 0; i < 4; i++)
#pragma unroll
    for (int j = 0; j < 4; j++) acc[i][j] = zero4();

  for (int k0 = 0; k0 < K; k0 += 32) {
#pragma unroll
    for (int i = 0; i < 2; i++) {
      int seg = w * 2 + i;
      int bo = seg * 1024 + lane * 16;
      int row = bo >> 6, col = (bo & 63) >> 1;
      GLDS16(A + (size_t)(m0 + row) * K + k0 + col, (char*)As + seg * 1024);
      GLDS16(Bw + (size_t)(n0 + row) * K + k0 + col, (char*)Bs + seg * 1024);
    }
    __syncthreads();
    short8 af[4], bfr[4];
#pragma unroll
    for (int i = 0; i < 4; i++) {
      af[i] = *(const short8*)&As[(wm + i * 16 + c) * 32 + quad * 8];
      bfr[i] = *(const short8*)&Bs[(wn + i * 16 + c) * 32 + quad * 8];
    }
#pragma unroll
    for (int mi = 0; mi < 4; mi++)
#pragma unroll
      for (int ni = 0; ni < 4; ni++) acc[mi][ni] = MFMA16(af[mi], bfr[ni], acc[mi][ni]);
    __syncthreads();
  }
#pragma unroll
  for (int mi = 0; mi < 4; mi++) {
    int rowb = m0 + wm + mi * 16 + quad * 4;
#pragma unroll
    for (int ni = 0; ni < 4; ni++) {
      int col = n0 + wn + ni * 16 + c;
#pragma unroll
      for (int r = 0; r < 4; r++) Out[(size_t)(rowb + r) * 1024 + col] = acc[mi][ni][r];
    }
  }
}

// ---------------------------------------------------------------- launch
extern "C" void kernel_launch(void* const* d_in, const int* in_sizes, int n_in,
                              void* d_out, int out_size, void* d_ws, size_t ws_size,
                              hipStream_t stream) {
  const float* query = (const float*)d_in[0];
  const float* enc = (const float*)d_in[1];
  const float* Wq = (const float*)d_in[2];
  const float* Wkva = (const float*)d_in[3];
  const float* ln_g = (const float*)d_in[4];
  const float* ln_b = (const float*)d_in[5];
  const float* Wkvb = (const float*)d_in[6];
  const float* Wout = (const float*)d_in[7];
  if (ws_size < 81264640) return;  // need ~77.5 MB scratch

  char* ws = (char*)d_ws;
  unsigned short* wq_bf = (unsigned short*)(ws + 0);         // 2 MB
  unsigned short* wa_bf = (unsigned short*)(ws + 2097152);   // 512 KB
  unsigned short* wb_bf = (unsigned short*)(ws + 2621440);   // 1 MB
  unsigned short* wo_bf = (unsigned short*)(ws + 3670016);   // 2 MB
  unsigned short* qproj = (unsigned short*)(ws + 5767168);   // 16 MB (B,H,SQ,64)
  unsigned short* cln = (unsigned short*)(ws + 22544384);    // 8 MB
  unsigned short* ebf_v = (unsigned short*)(ws + 30932992);  // 32 MB: E_bf, then V tiles
  unsigned short* qin_o = (unsigned short*)(ws + 64487424);  // 16 MB: Q_in bf16, then O
  unsigned short* kbuf = (unsigned short*)d_out;             // 32 MB: K tiles until final GEMM

  k_cast6<<<27392, 256, 0, stream>>>(enc, query, Wq, Wout, Wkvb, Wkva,
                                     ebf_v, qin_o, wq_bf, wo_bf, wb_bf, wa_bf);

  k_qproj<<<dim3(64, 8), 256, 0, stream>>>(qin_o, wq_bf, qproj);
  k_cln<<<256, 256, 0, stream>>>(ebf_v, wa_bf, ln_g, ln_b, cln);
  k_kv<<<dim3(128, 16), 256, 0, stream>>>(cln, wb_bf, kbuf, ebf_v);
  k_attn<<<dim3(16, 64), 128, 0, stream>>>(qproj, kbuf, ebf_v, qin_o);
  k_out<<<dim3(64, 8), 256, 0, stream>>>(qin_o, wo_bf, (float*)d_out);
}